// Round 9
// baseline (344.300 us; speedup 1.0000x reference)
//
#include <hip/hip_runtime.h>
#include <stdint.h>

#define NB 131072     // batch
#define MS 64         // samples per block
#define NT 512        // 8 waves; each wave owns a 32-col slice
#define ROWS 264      // shorts per LDS activation row (528 B, 16B-aligned)

typedef __bf16 bf16x8 __attribute__((ext_vector_type(8)));
typedef short  s16x8  __attribute__((ext_vector_type(8)));
typedef float  f32x4  __attribute__((ext_vector_type(4)));
typedef float  f32x2  __attribute__((ext_vector_type(2)));

static __device__ __forceinline__ short f2bf(float f){
  uint32_t u = __builtin_bit_cast(uint32_t, f);
  u = (u + 0x7fffu + ((u >> 16) & 1u)) >> 16;   // RNE
  return (short)(uint16_t)u;
}
static __device__ __forceinline__ float fast_tanh(float x){
  float e = __expf(2.0f * x);
  return 1.0f - 2.0f * __builtin_amdgcn_rcpf(e + 1.0f);
}
static __device__ __forceinline__ float rsum16(float v){
  v += __shfl_xor(v, 1);
  v += __shfl_xor(v, 2);
  v += __shfl_xor(v, 4);
  v += __shfl_xor(v, 8);
  return v;
}

// ---- GEMM core (R6-proven 64-VGPR shape): 64x32 out slice per wave, K=256.
// A from LDS, B inline from global (L2-hot). Layouts (m89/m92-verified):
//   A row=l&15, k=(l>>4)*8+e;  B col=l&15, k=(l>>4)*8+e;  D col=l&15, row=(l>>4)*4+r.
static __device__ __forceinline__ void gemm_core(
    const short* S_, const short* __restrict__ Wb,
    int w, int lm, int q, f32x4 acc[4][2])
{
#pragma unroll
  for (int mi=0;mi<4;mi++)
#pragma unroll
    for (int nj=0;nj<2;nj++)
      acc[mi][nj] = (f32x4){0.f,0.f,0.f,0.f};
  const short* ap = S_ + lm*ROWS + q*8;
  const short* bp = Wb + (32*w + lm)*256 + q*8;
#pragma unroll
  for (int ks=0; ks<8; ++ks){
    bf16x8 af[4], bfr[2];
#pragma unroll
    for (int mi=0;mi<4;mi++)
      af[mi] = *(const bf16x8*)(ap + 16*mi*ROWS + 32*ks);
    bfr[0] = *(const bf16x8*)(bp + 32*ks);
    bfr[1] = *(const bf16x8*)(bp + 16*256 + 32*ks);
#pragma unroll
    for (int mi=0;mi<4;mi++){
      acc[mi][0] = __builtin_amdgcn_mfma_f32_16x16x32_bf16(af[mi], bfr[0], acc[mi][0], 0, 0, 0);
      acc[mi][1] = __builtin_amdgcn_mfma_f32_16x16x32_bf16(af[mi], bfr[1], acc[mi][1], 0, 0, 0);
    }
  }
}

// ---- stage: act1 = tanh(x*W1^T + b1) -> bf16 LDS tile [64][256] (stride ROWS)
static __device__ __forceinline__ void stage_act(
    int tid, const float* __restrict__ W1, const float* __restrict__ b1,
    float x0, float x1, short* buf)
{
  const int s  = tid & 63;
  const int kg = tid >> 6;
#pragma unroll
  for (int it=0; it<4; ++it){
    const int k0 = (kg + 8*it) * 8;
    f32x4 wa = *(const f32x4*)(W1 + k0*2);
    f32x4 wb = *(const f32x4*)(W1 + k0*2 + 4);
    f32x4 wc = *(const f32x4*)(W1 + k0*2 + 8);
    f32x4 wd = *(const f32x4*)(W1 + k0*2 + 12);
    f32x4 ba = *(const f32x4*)(b1 + k0);
    f32x4 bb = *(const f32x4*)(b1 + k0 + 4);
    s16x8 p;
    p[0] = f2bf(fast_tanh(x0*wa.x + x1*wa.y + ba.x));
    p[1] = f2bf(fast_tanh(x0*wa.z + x1*wa.w + ba.y));
    p[2] = f2bf(fast_tanh(x0*wb.x + x1*wb.y + ba.z));
    p[3] = f2bf(fast_tanh(x0*wb.z + x1*wb.w + ba.w));
    p[4] = f2bf(fast_tanh(x0*wc.x + x1*wc.y + bb.x));
    p[5] = f2bf(fast_tanh(x0*wc.z + x1*wc.w + bb.y));
    p[6] = f2bf(fast_tanh(x0*wd.x + x1*wd.y + bb.z));
    p[7] = f2bf(fast_tanh(x0*wd.z + x1*wd.w + bb.w));
    *(s16x8*)(buf + s*ROWS + k0) = p;
  }
}

// ---- fwd epilogue: act2 = tanh(acc+b2); write derivative-weighted "d" back into S
// (act1 is recomputed later); row-reduce into rs[w][srow].
template<int ISH>
static __device__ __forceinline__ void epi_fwd(
    f32x4 acc[4][2], const float* __restrict__ b2, const float* __restrict__ W3,
    short* S_, int w, int lm, int q, float* __restrict__ rs)
{
  float b2v[2], w3v[2];
#pragma unroll
  for (int nj=0;nj<2;nj++){
    const int h = 32*w + 16*nj + lm;
    b2v[nj] = b2[h];
    w3v[nj] = ISH ? W3[h] : 0.f;
  }
#pragma unroll
  for (int mi=0;mi<4;mi++){
#pragma unroll
    for (int r=0;r<4;r++){
      const int srow = 16*mi + 4*q + r;
      float part = 0.f;
#pragma unroll
      for (int nj=0;nj<2;nj++){
        const int h = 32*w + 16*nj + lm;
        const float t = fast_tanh(acc[mi][nj][r] + b2v[nj]);
        float d;
        if (ISH){ part += w3v[nj]*t; d = w3v[nj]*(1.f - t*t); }
        else    { part += t*t;       d = t*(1.f - t*t); }
        S_[srow*ROWS + h] = f2bf(d);
      }
      const float tot = rsum16(part);
      if (lm == 0) rs[w*MS + srow] = tot;
    }
  }
}

// ---- bwd epilogue (u folded, act1 RECOMPUTED):
// g = sum_kc acc2*(1-a1^2)*(W1[kc,0]*p0 + W1[kc,1]*p1)
static __device__ __forceinline__ void epi_bwd(
    f32x4 acc[4][2], const float* __restrict__ W1, const float* __restrict__ b1,
    const float (* __restrict__ xsx)[2],
    int w, int lm, int q, const float* __restrict__ psv, float* __restrict__ gsred)
{
  f32x2 w1v[2];
  float b1v[2];
  int kc[2];
#pragma unroll
  for (int nj=0;nj<2;nj++){
    kc[nj] = 32*w + 16*nj + lm;
    w1v[nj] = *(const f32x2*)(W1 + 2*kc[nj]);
    b1v[nj] = b1[kc[nj]];
  }
#pragma unroll
  for (int mi=0;mi<4;mi++){
#pragma unroll
    for (int r=0;r<4;r++){
      const int srow = 16*mi + 4*q + r;
      const f32x2 xv = *(const f32x2*)(&xsx[srow][0]);   // broadcast (16 lanes same addr)
      const f32x2 p  = *(const f32x2*)(psv + 2*srow);
      float g = 0.f;
#pragma unroll
      for (int nj=0;nj<2;nj++){
        const float a1 = fast_tanh(xv.x*w1v[nj].x + xv.y*w1v[nj].y + b1v[nj]);
        const float fac = acc[mi][nj][r] * (1.f - a1*a1);
        g += fac * (w1v[nj].x * p.x + w1v[nj].y * p.y);
      }
      const float t0 = rsum16(g);
      if (lm == 0) gsred[w*MS + srow] = t0;
    }
  }
}

__global__ __launch_bounds__(NT, 8)   // force 64-VGPR cap -> 8 waves/SIMD eligible
void fused(const float* __restrict__ x,
           const float* __restrict__ VW1, const float* __restrict__ Vb1, const float* __restrict__ Vb2,
           const float* __restrict__ HW1, const float* __restrict__ Hb1, const float* __restrict__ Hb2,
           const float* __restrict__ HW3, const float* __restrict__ Hb3,
           const float* __restrict__ uW1, const float* __restrict__ ub1,
           const float* __restrict__ uW2, const float* __restrict__ ub2,
           const short* __restrict__ VW2bf, const short* __restrict__ VW2T,
           const short* __restrict__ HW2bf, const short* __restrict__ HW2T,
           float* __restrict__ out)
{
  // LDS: 33792 + 512 + 512 + 2048 + 2048 = 38912 B -> 4 blocks/CU
  __shared__ __attribute__((aligned(16))) short S[MS*ROWS];
  __shared__ float xs[MS][2];
  __shared__ float psv[MS][2];      // (f0, f1+u) per sample
  __shared__ float red[8][MS];      // u-net partials, then rX (fwd reduction)
  __shared__ float gX[8][MS];       // bwd reduction

  const int tid = (int)threadIdx.x;
  const int w = tid >> 6, l = tid & 63, lm = l & 15, q = l >> 4;
  const int s0 = (int)blockIdx.x * MS;

  if (tid < 2*MS) ((float*)xs)[tid] = x[s0*2 + tid];
  __syncthreads();                                   // B1

  const float x0 = xs[tid & 63][0], x1 = xs[tid & 63][1];

  f32x4 acc[4][2];

  // ---- P1: u-net partials -> red ; V act1 staging -> S
  {
    float up = 0.f;
    const int g = tid >> 6;
    const int h0 = 32 * g;
#pragma unroll 8
    for (int i=0;i<32;i++){
      const int h = h0 + i;
      up += uW2[h] * fast_tanh(x0*uW1[2*h] + x1*uW1[2*h+1] + ub1[h]);
    }
    red[g][tid & 63] = up;
  }
  stage_act(tid, VW1, Vb1, x0, x1, S);
  __syncthreads();                                   // B2

  // ---- P2: finalize u -> psv (red becomes free); gemm1V reads S
  if (tid < MS){
    const int s = tid;
    float us = 0.f;
#pragma unroll
    for (int j=0;j<8;j++) us += red[j][s];
    const float u = fast_tanh(us + ub2[0]);
    const float xx0 = xs[s][0], xx1 = xs[s][1];
    psv[s][0] = xx1;                          // f0
    psv[s][1] = -sinf(xx0) - 0.1f*xx1 + u;    // f1 + u
    out[s0 + s] = u;
  }
  gemm_core(S, VW2bf, w, lm, q, acc);
  __syncthreads();                                   // B3 (S reads done; psv/red settled)

  // ---- P3: epi_fwdV overwrites S with dV, reduces into red
  epi_fwd<0>(acc, Vb2, (const float*)nullptr, S, w, lm, q, &red[0][0]);
  __syncthreads();                                   // B4

  // ---- P4: gemm2V reads S; epi_bwdV recomputes a1V
  gemm_core(S, VW2T, w, lm, q, acc);
  epi_bwd(acc, VW1, Vb1, xs, w, lm, q, &psv[0][0], &gX[0][0]);
  __syncthreads();                                   // B5 (S reads done)

  // ---- P5: V outputs; H act1 staging -> S
  if (tid < MS){
    const int s = tid;
    float sv=0.f, vd=0.f;
#pragma unroll
    for (int j=0;j<8;j++){ sv += red[j][s]; vd += gX[j][s]; }
    out[NB + s0 + s]   = 0.5f * sv;   // V
    out[2*NB + s0 + s] = vd;          // Vdot (u folded)
  }
  stage_act(tid, HW1, Hb1, x0, x1, S);
  __syncthreads();                                   // B6

  // ---- P6: gemm1H
  gemm_core(S, HW2bf, w, lm, q, acc);
  __syncthreads();                                   // B7

  // ---- P7: epi_fwdH overwrites S with dH
  epi_fwd<1>(acc, Hb2, HW3, S, w, lm, q, &red[0][0]);
  __syncthreads();                                   // B8

  // ---- P8: gemm2H; epi_bwdH
  gemm_core(S, HW2T, w, lm, q, acc);
  epi_bwd(acc, HW1, Hb1, xs, w, lm, q, &psv[0][0], &gX[0][0]);
  __syncthreads();                                   // B9

  // ---- P9: H outputs
  if (tid < MS){
    const int s = tid;
    float hp=0.f, hd=0.f;
#pragma unroll
    for (int j=0;j<8;j++){ hp += red[j][s]; hd += gX[j][s]; }
    const float H  = fast_tanh(hp + Hb3[0]);
    out[3*NB + s0 + s] = H;
    out[4*NB + s0 + s] = (1.f - H*H) * hd;  // Hdot
  }
}

// ---- pre-kernel: fp32 weights -> bf16 row-major + bf16 transposed copies in d_ws
__global__ __launch_bounds__(256)
void cvt_w(const float* __restrict__ VW2, const float* __restrict__ HW2, short* __restrict__ ws)
{
  __shared__ short t[64][65];
  const int bx   = (int)blockIdx.x;       // 0..31
  const int m    = bx >> 4;               // 0=V, 1=H
  const int tile = bx & 15;
  const int tr = tile >> 2, tc = tile & 3;
  const float* __restrict__ src = m ? HW2 : VW2;
  short* __restrict__ dN = ws + m * 131072;
  short* __restrict__ dT = dN + 65536;
  const int tid = (int)threadIdx.x;
  const int ri = tid >> 2;                // 0..63 local row
  const int cc = (tid & 3) * 16;          // local col chunk
  const int gr = tr*64 + ri;
#pragma unroll
  for (int j=0;j<16;j++){
    const int gc = tc*64 + cc + j;
    const short b = f2bf(src[gr*256 + gc]);
    dN[gr*256 + gc] = b;
    t[cc + j][ri] = b;
  }
  __syncthreads();
  const int cr = tid >> 2;                // local transposed row (= source col)
#pragma unroll
  for (int j=0;j<16;j++){
    const int sr = cc + j;                // source row local
    dT[(tc*64 + cr)*256 + tr*64 + sr] = t[cr][sr];
  }
}

extern "C" void kernel_launch(void* const* d_in, const int* in_sizes, int n_in,
                              void* d_out, int out_size, void* d_ws, size_t ws_size,
                              hipStream_t stream)
{
  const float* x   = (const float*)d_in[0];
  const float* VW1 = (const float*)d_in[1];
  const float* Vb1 = (const float*)d_in[2];
  const float* VW2 = (const float*)d_in[3];
  const float* Vb2 = (const float*)d_in[4];
  const float* HW1 = (const float*)d_in[5];
  const float* Hb1 = (const float*)d_in[6];
  const float* HW2 = (const float*)d_in[7];
  const float* Hb2 = (const float*)d_in[8];
  const float* HW3 = (const float*)d_in[9];
  const float* Hb3 = (const float*)d_in[10];
  const float* uW1 = (const float*)d_in[11];
  const float* ub1 = (const float*)d_in[12];
  const float* uW2 = (const float*)d_in[13];
  const float* ub2 = (const float*)d_in[14];

  short* wsbf = (short*)d_ws;             // needs 4*65536*2 = 512 KB of d_ws

  cvt_w<<<32, 256, 0, stream>>>(VW2, HW2, wsbf);
  fused<<<NB/MS, NT, 0, stream>>>(x, VW1, Vb1, Vb2, HW1, Hb1, Hb2, HW3, Hb3,
                                  uW1, ub1, uW2, ub2,
                                  wsbf, wsbf + 65536, wsbf + 131072, wsbf + 196608,
                                  (float*)d_out);
}

// Round 10
// 293.409 us; speedup vs baseline: 1.1734x; 1.1734x over previous
//
#include <hip/hip_runtime.h>
#include <stdint.h>

#define NB 131072     // batch
#define MS 64         // samples per block
#define NT 512        // 8 waves; each wave owns a 32-col slice
#define ROWS 264      // shorts per LDS activation row (528 B, 16B-aligned)

typedef __bf16 bf16x8 __attribute__((ext_vector_type(8)));
typedef short  s16x8  __attribute__((ext_vector_type(8)));
typedef float  f32x4  __attribute__((ext_vector_type(4)));
typedef float  f32x2  __attribute__((ext_vector_type(2)));

static __device__ __forceinline__ short f2bf(float f){
  uint32_t u = __builtin_bit_cast(uint32_t, f);
  u = (u + 0x7fffu + ((u >> 16) & 1u)) >> 16;   // RNE
  return (short)(uint16_t)u;
}
static __device__ __forceinline__ float fast_tanh(float x){
  float e = __expf(2.0f * x);
  return 1.0f - 2.0f * __builtin_amdgcn_rcpf(e + 1.0f);
}
static __device__ __forceinline__ float rsum16(float v){
  v += __shfl_xor(v, 1);
  v += __shfl_xor(v, 2);
  v += __shfl_xor(v, 4);
  v += __shfl_xor(v, 8);
  return v;
}

// ---- GEMM core (R6-proven 64-VGPR shape): 64x32 out slice per wave, K=256.
// A from LDS, B inline from global (L2-hot). Layouts (m89/m92-verified):
//   A row=l&15, k=(l>>4)*8+e;  B col=l&15, k=(l>>4)*8+e;  D col=l&15, row=(l>>4)*4+r.
static __device__ __forceinline__ void gemm_core(
    const short* S_, const short* __restrict__ Wb,
    int w, int lm, int q, f32x4 acc[4][2])
{
#pragma unroll
  for (int mi=0;mi<4;mi++)
#pragma unroll
    for (int nj=0;nj<2;nj++)
      acc[mi][nj] = (f32x4){0.f,0.f,0.f,0.f};
  const short* ap = S_ + lm*ROWS + q*8;
  const short* bp = Wb + (32*w + lm)*256 + q*8;
#pragma unroll
  for (int ks=0; ks<8; ++ks){
    bf16x8 af[4], bfr[2];
#pragma unroll
    for (int mi=0;mi<4;mi++)
      af[mi] = *(const bf16x8*)(ap + 16*mi*ROWS + 32*ks);
    bfr[0] = *(const bf16x8*)(bp + 32*ks);
    bfr[1] = *(const bf16x8*)(bp + 16*256 + 32*ks);
#pragma unroll
    for (int mi=0;mi<4;mi++){
      acc[mi][0] = __builtin_amdgcn_mfma_f32_16x16x32_bf16(af[mi], bfr[0], acc[mi][0], 0, 0, 0);
      acc[mi][1] = __builtin_amdgcn_mfma_f32_16x16x32_bf16(af[mi], bfr[1], acc[mi][1], 0, 0, 0);
    }
  }
}

// ---- stage: act1 = tanh(x*W1^T + b1) -> bf16 LDS tile [64][256] (stride ROWS)
static __device__ __forceinline__ void stage_act(
    int tid, const float* __restrict__ W1, const float* __restrict__ b1,
    float x0, float x1, short* buf)
{
  const int s  = tid & 63;
  const int kg = tid >> 6;
#pragma unroll
  for (int it=0; it<4; ++it){
    const int k0 = (kg + 8*it) * 8;
    f32x4 wa = *(const f32x4*)(W1 + k0*2);
    f32x4 wb = *(const f32x4*)(W1 + k0*2 + 4);
    f32x4 wc = *(const f32x4*)(W1 + k0*2 + 8);
    f32x4 wd = *(const f32x4*)(W1 + k0*2 + 12);
    f32x4 ba = *(const f32x4*)(b1 + k0);
    f32x4 bb = *(const f32x4*)(b1 + k0 + 4);
    s16x8 p;
    p[0] = f2bf(fast_tanh(x0*wa.x + x1*wa.y + ba.x));
    p[1] = f2bf(fast_tanh(x0*wa.z + x1*wa.w + ba.y));
    p[2] = f2bf(fast_tanh(x0*wb.x + x1*wb.y + ba.z));
    p[3] = f2bf(fast_tanh(x0*wb.z + x1*wb.w + ba.w));
    p[4] = f2bf(fast_tanh(x0*wc.x + x1*wc.y + bb.x));
    p[5] = f2bf(fast_tanh(x0*wc.z + x1*wc.w + bb.y));
    p[6] = f2bf(fast_tanh(x0*wd.x + x1*wd.y + bb.z));
    p[7] = f2bf(fast_tanh(x0*wd.z + x1*wd.w + bb.w));
    *(s16x8*)(buf + s*ROWS + k0) = p;
  }
}

// ---- fwd epilogue: act2 = tanh(acc+b2); write derivative-weighted "d" back into S
// (act1 recomputed later); row-reduce into rs[w][srow].
template<int ISH>
static __device__ __forceinline__ void epi_fwd(
    f32x4 acc[4][2], const float* __restrict__ b2, const float* __restrict__ W3,
    short* S_, int w, int lm, int q, float* __restrict__ rs)
{
  float b2v[2], w3v[2];
#pragma unroll
  for (int nj=0;nj<2;nj++){
    const int h = 32*w + 16*nj + lm;
    b2v[nj] = b2[h];
    w3v[nj] = ISH ? W3[h] : 0.f;
  }
#pragma unroll
  for (int mi=0;mi<4;mi++){
#pragma unroll
    for (int r=0;r<4;r++){
      const int srow = 16*mi + 4*q + r;
      float part = 0.f;
#pragma unroll
      for (int nj=0;nj<2;nj++){
        const int h = 32*w + 16*nj + lm;
        const float t = fast_tanh(acc[mi][nj][r] + b2v[nj]);
        float d;
        if (ISH){ part += w3v[nj]*t; d = w3v[nj]*(1.f - t*t); }
        else    { part += t*t;       d = t*(1.f - t*t); }
        S_[srow*ROWS + h] = f2bf(d);
      }
      const float tot = rsum16(part);
      if (lm == 0) rs[w*MS + srow] = tot;
    }
  }
}

// ---- bwd epilogue (u folded, act1 RECOMPUTED — R9-validated algebra):
// g = sum_kc acc2*(1-a1^2)*(W1[kc,0]*p0 + W1[kc,1]*p1)
static __device__ __forceinline__ void epi_bwd(
    f32x4 acc[4][2], const float* __restrict__ W1, const float* __restrict__ b1,
    const float (* __restrict__ xsx)[2],
    int w, int lm, int q, const float* __restrict__ psv, float* __restrict__ gsred)
{
  f32x2 w1v[2];
  float b1v[2];
  int kc[2];
#pragma unroll
  for (int nj=0;nj<2;nj++){
    kc[nj] = 32*w + 16*nj + lm;
    w1v[nj] = *(const f32x2*)(W1 + 2*kc[nj]);
    b1v[nj] = b1[kc[nj]];
  }
#pragma unroll
  for (int mi=0;mi<4;mi++){
#pragma unroll
    for (int r=0;r<4;r++){
      const int srow = 16*mi + 4*q + r;
      const f32x2 xv = *(const f32x2*)(&xsx[srow][0]);   // broadcast read
      const f32x2 p  = *(const f32x2*)(psv + 2*srow);
      float g = 0.f;
#pragma unroll
      for (int nj=0;nj<2;nj++){
        const float a1 = fast_tanh(xv.x*w1v[nj].x + xv.y*w1v[nj].y + b1v[nj]);
        const float fac = acc[mi][nj][r] * (1.f - a1*a1);
        g += fac * (w1v[nj].x * p.x + w1v[nj].y * p.y);
      }
      const float t0 = rsum16(g);
      if (lm == 0) gsred[w*MS + srow] = t0;
    }
  }
}

// Split-path kernel: even blocks do the V net, odd blocks the H net, for the
// same 64 samples (bid>>1). Co-resident V/H blocks sit in different phases ->
// pipe mixing without occupancy change; 5 barriers/block instead of 9.
__global__ __launch_bounds__(NT, 4)
void fused(const float* __restrict__ x,
           const float* __restrict__ VW1, const float* __restrict__ Vb1, const float* __restrict__ Vb2,
           const float* __restrict__ HW1, const float* __restrict__ Hb1, const float* __restrict__ Hb2,
           const float* __restrict__ HW3, const float* __restrict__ Hb3,
           const float* __restrict__ uW1, const float* __restrict__ ub1,
           const float* __restrict__ uW2, const float* __restrict__ ub2,
           const short* __restrict__ VW2bf, const short* __restrict__ VW2T,
           const short* __restrict__ HW2bf, const short* __restrict__ HW2T,
           float* __restrict__ out)
{
  // LDS: 33792 + 512 + 512 + 2048 + 2048 = 38912 B
  __shared__ __attribute__((aligned(16))) short S[MS*ROWS];
  __shared__ float xs[MS][2];
  __shared__ float psv[MS][2];      // (f0, f1+u) per sample
  __shared__ float red[8][MS];      // u-net partials, then fwd reduction
  __shared__ float gX[8][MS];       // bwd reduction

  const int tid = (int)threadIdx.x;
  const int w = tid >> 6, l = tid & 63, lm = l & 15, q = l >> 4;
  const int bid = (int)blockIdx.x;
  const int path = bid & 1;                 // 0 = V net, 1 = H net
  const int s0 = (bid >> 1) * MS;

  const float* __restrict__ W1 = path ? HW1 : VW1;
  const float* __restrict__ b1 = path ? Hb1 : Vb1;

  if (tid < 2*MS) ((float*)xs)[tid] = x[s0*2 + tid];
  __syncthreads();                                   // B1

  const float x0 = xs[tid & 63][0], x1 = xs[tid & 63][1];

  f32x4 acc[4][2];

  // ---- P1: u-net partials -> red ; act1 staging -> S
  {
    float up = 0.f;
    const int g = tid >> 6;
    const int h0 = 32 * g;
#pragma unroll 8
    for (int i=0;i<32;i++){
      const int h = h0 + i;
      up += uW2[h] * fast_tanh(x0*uW1[2*h] + x1*uW1[2*h+1] + ub1[h]);
    }
    red[g][tid & 63] = up;
  }
  stage_act(tid, W1, b1, x0, x1, S);
  __syncthreads();                                   // B2

  // ---- P2: finalize u -> psv (V blocks also write u); gemm1 reads S
  if (tid < MS){
    const int s = tid;
    float us = 0.f;
#pragma unroll
    for (int j=0;j<8;j++) us += red[j][s];
    const float u = fast_tanh(us + ub2[0]);
    const float xx0 = xs[s][0], xx1 = xs[s][1];
    psv[s][0] = xx1;                          // f0
    psv[s][1] = -sinf(xx0) - 0.1f*xx1 + u;    // f1 + u
    if (path == 0) out[s0 + s] = u;
  }

  if (path == 0){
    // ================= V net =================
    gemm_core(S, VW2bf, w, lm, q, acc);
    __syncthreads();                                 // B3 (S reads done; red free)
    epi_fwd<0>(acc, Vb2, (const float*)nullptr, S, w, lm, q, &red[0][0]);
    __syncthreads();                                 // B4 (S now holds dV)
    gemm_core(S, VW2T, w, lm, q, acc);
    epi_bwd(acc, VW1, Vb1, xs, w, lm, q, &psv[0][0], &gX[0][0]);
    __syncthreads();                                 // B5
    if (tid < MS){
      const int s = tid;
      float sv=0.f, vd=0.f;
#pragma unroll
      for (int j=0;j<8;j++){ sv += red[j][s]; vd += gX[j][s]; }
      out[NB + s0 + s]   = 0.5f * sv;   // V
      out[2*NB + s0 + s] = vd;          // Vdot (u folded)
    }
  } else {
    // ================= H net =================
    gemm_core(S, HW2bf, w, lm, q, acc);
    __syncthreads();                                 // B3
    epi_fwd<1>(acc, Hb2, HW3, S, w, lm, q, &red[0][0]);
    __syncthreads();                                 // B4 (S now holds dH)
    gemm_core(S, HW2T, w, lm, q, acc);
    epi_bwd(acc, HW1, Hb1, xs, w, lm, q, &psv[0][0], &gX[0][0]);
    __syncthreads();                                 // B5
    if (tid < MS){
      const int s = tid;
      float hp=0.f, hd=0.f;
#pragma unroll
      for (int j=0;j<8;j++){ hp += red[j][s]; hd += gX[j][s]; }
      const float H  = fast_tanh(hp + Hb3[0]);
      out[3*NB + s0 + s] = H;
      out[4*NB + s0 + s] = (1.f - H*H) * hd;  // Hdot
    }
  }
}

// ---- pre-kernel: fp32 weights -> bf16 row-major + bf16 transposed copies in d_ws
__global__ __launch_bounds__(256)
void cvt_w(const float* __restrict__ VW2, const float* __restrict__ HW2, short* __restrict__ ws)
{
  __shared__ short t[64][65];
  const int bx   = (int)blockIdx.x;       // 0..31
  const int m    = bx >> 4;               // 0=V, 1=H
  const int tile = bx & 15;
  const int tr = tile >> 2, tc = tile & 3;
  const float* __restrict__ src = m ? HW2 : VW2;
  short* __restrict__ dN = ws + m * 131072;
  short* __restrict__ dT = dN + 65536;
  const int tid = (int)threadIdx.x;
  const int ri = tid >> 2;                // 0..63 local row
  const int cc = (tid & 3) * 16;          // local col chunk
  const int gr = tr*64 + ri;
#pragma unroll
  for (int j=0;j<16;j++){
    const int gc = tc*64 + cc + j;
    const short b = f2bf(src[gr*256 + gc]);
    dN[gr*256 + gc] = b;
    t[cc + j][ri] = b;
  }
  __syncthreads();
  const int cr = tid >> 2;                // local transposed row (= source col)
#pragma unroll
  for (int j=0;j<16;j++){
    const int sr = cc + j;                // source row local
    dT[(tc*64 + cr)*256 + tr*64 + sr] = t[cr][sr];
  }
}

extern "C" void kernel_launch(void* const* d_in, const int* in_sizes, int n_in,
                              void* d_out, int out_size, void* d_ws, size_t ws_size,
                              hipStream_t stream)
{
  const float* x   = (const float*)d_in[0];
  const float* VW1 = (const float*)d_in[1];
  const float* Vb1 = (const float*)d_in[2];
  const float* VW2 = (const float*)d_in[3];
  const float* Vb2 = (const float*)d_in[4];
  const float* HW1 = (const float*)d_in[5];
  const float* Hb1 = (const float*)d_in[6];
  const float* HW2 = (const float*)d_in[7];
  const float* Hb2 = (const float*)d_in[8];
  const float* HW3 = (const float*)d_in[9];
  const float* Hb3 = (const float*)d_in[10];
  const float* uW1 = (const float*)d_in[11];
  const float* ub1 = (const float*)d_in[12];
  const float* uW2 = (const float*)d_in[13];
  const float* ub2 = (const float*)d_in[14];

  short* wsbf = (short*)d_ws;             // needs 4*65536*2 = 512 KB of d_ws

  cvt_w<<<32, 256, 0, stream>>>(VW2, HW2, wsbf);
  fused<<<(NB/MS)*2, NT, 0, stream>>>(x, VW1, Vb1, Vb2, HW1, Hb1, Hb2, HW3, Hb3,
                                      uW1, ub1, uW2, ub2,
                                      wsbf, wsbf + 65536, wsbf + 131072, wsbf + 196608,
                                      (float*)d_out);
}

// Round 11
// 281.075 us; speedup vs baseline: 1.2249x; 1.0439x over previous
//
#include <hip/hip_runtime.h>
#include <stdint.h>

#define NB 131072     // batch
#define MS 64         // samples per block
#define NT 512        // 8 waves; each wave owns a 32-col slice
#define ROWS 264      // shorts per LDS activation row (528 B, 16B-aligned)

typedef __bf16 bf16x8 __attribute__((ext_vector_type(8)));
typedef float  f32x4  __attribute__((ext_vector_type(4)));
typedef float  f32x2  __attribute__((ext_vector_type(2)));

static __device__ __forceinline__ short f2bf(float f){
  __bf16 h = (__bf16)f;                    // native cvt (compiler emits v_cvt_pk_bf16_f32 pairs)
  return __builtin_bit_cast(short, h);
}
static __device__ __forceinline__ float fast_tanh(float x){
  float e = __expf(2.0f * x);
  return 1.0f - 2.0f * __builtin_amdgcn_rcpf(e + 1.0f);
}
static __device__ __forceinline__ float rsum16(float v){
  v += __shfl_xor(v, 1);
  v += __shfl_xor(v, 2);
  v += __shfl_xor(v, 4);
  v += __shfl_xor(v, 8);
  return v;
}

// ---- GEMM core (R6-proven shape): 64x32 out slice per wave, K=256.
// A from LDS, B inline from global (L2-hot). Layouts (m89/m92-verified):
//   A row=l&15, k=(l>>4)*8+e;  B col=l&15, k=(l>>4)*8+e;  D col=l&15, row=(l>>4)*4+r.
static __device__ __forceinline__ void gemm_core(
    const short* S_, const short* __restrict__ Wb,
    int w, int lm, int q, f32x4 (&acc)[4][2])
{
#pragma unroll
  for (int mi=0;mi<4;mi++)
#pragma unroll
    for (int nj=0;nj<2;nj++)
      acc[mi][nj] = (f32x4){0.f,0.f,0.f,0.f};
  const short* ap = S_ + lm*ROWS + q*8;
  const short* bp = Wb + (32*w + lm)*256 + q*8;
#pragma unroll
  for (int ks=0; ks<8; ++ks){
    bf16x8 af[4], bfr[2];
#pragma unroll
    for (int mi=0;mi<4;mi++)
      af[mi] = *(const bf16x8*)(ap + 16*mi*ROWS + 32*ks);
    bfr[0] = *(const bf16x8*)(bp + 32*ks);
    bfr[1] = *(const bf16x8*)(bp + 16*256 + 32*ks);
#pragma unroll
    for (int mi=0;mi<4;mi++){
      acc[mi][0] = __builtin_amdgcn_mfma_f32_16x16x32_bf16(af[mi], bfr[0], acc[mi][0], 0, 0, 0);
      acc[mi][1] = __builtin_amdgcn_mfma_f32_16x16x32_bf16(af[mi], bfr[1], acc[mi][1], 0, 0, 0);
    }
  }
}

// ---- stage: act1 = tanh(x*W1^T + b1) -> bf16 LDS tile [64][256] (stride ROWS)
static __device__ __forceinline__ void stage_act(
    int tid, const float* __restrict__ W1, const float* __restrict__ b1,
    float x0, float x1, short* buf)
{
  const int s  = tid & 63;
  const int kg = tid >> 6;
#pragma unroll
  for (int it=0; it<4; ++it){
    const int k0 = (kg + 8*it) * 8;
    f32x4 wa = *(const f32x4*)(W1 + k0*2);
    f32x4 wb = *(const f32x4*)(W1 + k0*2 + 4);
    f32x4 wc = *(const f32x4*)(W1 + k0*2 + 8);
    f32x4 wd = *(const f32x4*)(W1 + k0*2 + 12);
    f32x4 ba = *(const f32x4*)(b1 + k0);
    f32x4 bb = *(const f32x4*)(b1 + k0 + 4);
    bf16x8 p;
    p[0] = (__bf16)fast_tanh(x0*wa.x + x1*wa.y + ba.x);
    p[1] = (__bf16)fast_tanh(x0*wa.z + x1*wa.w + ba.y);
    p[2] = (__bf16)fast_tanh(x0*wb.x + x1*wb.y + ba.z);
    p[3] = (__bf16)fast_tanh(x0*wb.z + x1*wb.w + ba.w);
    p[4] = (__bf16)fast_tanh(x0*wc.x + x1*wc.y + bb.x);
    p[5] = (__bf16)fast_tanh(x0*wc.z + x1*wc.w + bb.y);
    p[6] = (__bf16)fast_tanh(x0*wd.x + x1*wd.y + bb.z);
    p[7] = (__bf16)fast_tanh(x0*wd.z + x1*wd.w + bb.w);
    *(bf16x8*)(buf + s*ROWS + k0) = p;
  }
}

// ---- fwd epilogue: act2 = tanh(acc+b2); write derivative-weighted "d" back into S;
// row-reduce (V: sum act2^2, H: sum W3*act2) into rs[w][srow].
template<int ISH>
static __device__ __forceinline__ void epi_fwd(
    f32x4 (&acc)[4][2], const float* __restrict__ b2, const float* __restrict__ W3,
    short* S_, int w, int lm, int q, float* __restrict__ rs)
{
  float b2v[2], w3v[2];
#pragma unroll
  for (int nj=0;nj<2;nj++){
    const int h = 32*w + 16*nj + lm;
    b2v[nj] = b2[h];
    w3v[nj] = ISH ? W3[h] : 0.f;
  }
#pragma unroll
  for (int mi=0;mi<4;mi++){
#pragma unroll
    for (int r=0;r<4;r++){
      const int srow = 16*mi + 4*q + r;
      float part = 0.f;
#pragma unroll
      for (int nj=0;nj<2;nj++){
        const int h = 32*w + 16*nj + lm;
        const float t = fast_tanh(acc[mi][nj][r] + b2v[nj]);
        float d;
        if (ISH){ part += w3v[nj]*t; d = w3v[nj]*(1.f - t*t); }
        else    { part += t*t;       d = t*(1.f - t*t); }
        S_[srow*ROWS + h] = f2bf(d);
      }
      const float tot = rsum16(part);
      if (lm == 0) rs[w*MS + srow] = tot;
    }
  }
}

// ---- bwd epilogue (u folded, act1 RECOMPUTED — R9/R10-validated algebra):
// g = sum_kc acc2*(1-a1^2)*(W1[kc,0]*p0 + W1[kc,1]*p1)
static __device__ __forceinline__ void epi_bwd(
    f32x4 (&acc)[4][2], const float* __restrict__ W1, const float* __restrict__ b1,
    const float (* __restrict__ xsx)[2],
    int w, int lm, int q, const float* __restrict__ psv, float* __restrict__ gsred)
{
  f32x2 w1v[2];
  float b1v[2];
#pragma unroll
  for (int nj=0;nj<2;nj++){
    const int kc = 32*w + 16*nj + lm;
    w1v[nj] = *(const f32x2*)(W1 + 2*kc);
    b1v[nj] = b1[kc];
  }
#pragma unroll
  for (int mi=0;mi<4;mi++){
#pragma unroll
    for (int r=0;r<4;r++){
      const int srow = 16*mi + 4*q + r;
      const f32x2 xv = *(const f32x2*)(&xsx[srow][0]);   // broadcast read
      const f32x2 p  = *(const f32x2*)(psv + 2*srow);
      float g = 0.f;
#pragma unroll
      for (int nj=0;nj<2;nj++){
        const float a1 = fast_tanh(xv.x*w1v[nj].x + xv.y*w1v[nj].y + b1v[nj]);
        const float fac = acc[mi][nj][r] * (1.f - a1*a1);
        g += fac * (w1v[nj].x * p.x + w1v[nj].y * p.y);
      }
      const float t0 = rsum16(g);
      if (lm == 0) gsred[w*MS + srow] = t0;
    }
  }
}

// V/H cross-pipelined block: every inter-barrier region issues one net's GEMM
// (MFMA pipe + L2 loads) and the OTHER net's epilogue/staging (VALU pipe) —
// guaranteed in-block overlap instead of hoping the scheduler de-phases blocks.
__global__ __launch_bounds__(NT, 2)   // 256-VGPR cap: both accs (64) + temps fit, no spill (R8 precedent)
void fused(const float* __restrict__ x,
           const float* __restrict__ VW1, const float* __restrict__ Vb1, const float* __restrict__ Vb2,
           const float* __restrict__ HW1, const float* __restrict__ Hb1, const float* __restrict__ Hb2,
           const float* __restrict__ HW3, const float* __restrict__ Hb3,
           const float* __restrict__ uW1, const float* __restrict__ ub1,
           const float* __restrict__ uW2, const float* __restrict__ ub2,
           const short* __restrict__ VW2bf, const short* __restrict__ VW2T,
           const short* __restrict__ HW2bf, const short* __restrict__ HW2T,
           float* __restrict__ out)
{
  // LDS: 2*33792 + 512 + 512 + 4*2048 = 76.6 KB -> 2 blocks/CU (16 waves)
  __shared__ __attribute__((aligned(16))) short SV[MS*ROWS];
  __shared__ __attribute__((aligned(16))) short SH[MS*ROWS];
  __shared__ float xs[MS][2];
  __shared__ float psv[MS][2];      // (f0, f1+u) per sample
  __shared__ float redA[8][MS];     // u-net partials (P1-P2), then gV (P5-P6)
  __shared__ float redV[8][MS];     // V fwd reduction
  __shared__ float redH[8][MS];     // H fwd reduction
  __shared__ float gH[8][MS];       // H bwd reduction

  const int tid = (int)threadIdx.x;
  const int w = tid >> 6, l = tid & 63, lm = l & 15, q = l >> 4;
  const int s0 = (int)blockIdx.x * MS;

  if (tid < 2*MS) ((float*)xs)[tid] = x[s0*2 + tid];
  __syncthreads();                                   // B1

  const float x0 = xs[tid & 63][0], x1 = xs[tid & 63][1];

  f32x4 accV[4][2], accH[4][2];

  // ---- P1: u-net partials -> redA ; V act1 staging -> SV   [pure VALU]
  {
    float up = 0.f;
    const int g = tid >> 6;
    const int h0 = 32 * g;
#pragma unroll 8
    for (int i=0;i<32;i++){
      const int h = h0 + i;
      up += uW2[h] * fast_tanh(x0*uW1[2*h] + x1*uW1[2*h+1] + ub1[h]);
    }
    redA[g][tid & 63] = up;
  }
  stage_act(tid, VW1, Vb1, x0, x1, SV);
  __syncthreads();                                   // B2

  // ---- P2: gemm1_V [MFMA] || H staging + u finalize [VALU]
  gemm_core(SV, VW2bf, w, lm, q, accV);
  stage_act(tid, HW1, Hb1, x0, x1, SH);
  if (tid < MS){
    const int s = tid;
    float us = 0.f;
#pragma unroll
    for (int j=0;j<8;j++) us += redA[j][s];
    const float u = fast_tanh(us + ub2[0]);
    const float xx0 = xs[s][0], xx1 = xs[s][1];
    psv[s][0] = xx1;                          // f0
    psv[s][1] = -sinf(xx0) - 0.1f*xx1 + u;    // f1 + u
    out[s0 + s] = u;
  }
  __syncthreads();                                   // B3

  // ---- P3: gemm1_H [MFMA] || epi_fwd_V (SV := dV, redV) [VALU]
  gemm_core(SH, HW2bf, w, lm, q, accH);
  epi_fwd<0>(accV, Vb2, (const float*)nullptr, SV, w, lm, q, &redV[0][0]);
  __syncthreads();                                   // B4

  // ---- P4: gemm2_V [MFMA] || epi_fwd_H (SH := dH, redH) [VALU]
  gemm_core(SV, VW2T, w, lm, q, accV);
  epi_fwd<1>(accH, Hb2, HW3, SH, w, lm, q, &redH[0][0]);
  __syncthreads();                                   // B5

  // ---- P5: gemm2_H [MFMA] || epi_bwd_V -> gV(redA) [VALU]
  gemm_core(SH, HW2T, w, lm, q, accH);
  epi_bwd(accV, VW1, Vb1, xs, w, lm, q, &psv[0][0], &redA[0][0]);
  __syncthreads();                                   // B6

  // ---- P6: epi_bwd_H -> gH [VALU] || V outputs
  epi_bwd(accH, HW1, Hb1, xs, w, lm, q, &psv[0][0], &gH[0][0]);
  if (tid < MS){
    const int s = tid;
    float sv=0.f, vd=0.f;
#pragma unroll
    for (int j=0;j<8;j++){ sv += redV[j][s]; vd += redA[j][s]; }
    out[NB + s0 + s]   = 0.5f * sv;   // V
    out[2*NB + s0 + s] = vd;          // Vdot (u folded)
  }
  __syncthreads();                                   // B7

  // ---- P7: H outputs
  if (tid < MS){
    const int s = tid;
    float hp=0.f, hd=0.f;
#pragma unroll
    for (int j=0;j<8;j++){ hp += redH[j][s]; hd += gH[j][s]; }
    const float H  = fast_tanh(hp + Hb3[0]);
    out[3*NB + s0 + s] = H;
    out[4*NB + s0 + s] = (1.f - H*H) * hd;  // Hdot
  }
}

// ---- pre-kernel: fp32 weights -> bf16 row-major + bf16 transposed copies in d_ws
__global__ __launch_bounds__(256)
void cvt_w(const float* __restrict__ VW2, const float* __restrict__ HW2, short* __restrict__ ws)
{
  __shared__ short t[64][65];
  const int bx   = (int)blockIdx.x;       // 0..31
  const int m    = bx >> 4;               // 0=V, 1=H
  const int tile = bx & 15;
  const int tr = tile >> 2, tc = tile & 3;
  const float* __restrict__ src = m ? HW2 : VW2;
  short* __restrict__ dN = ws + m * 131072;
  short* __restrict__ dT = dN + 65536;
  const int tid = (int)threadIdx.x;
  const int ri = tid >> 2;                // 0..63 local row
  const int cc = (tid & 3) * 16;          // local col chunk
  const int gr = tr*64 + ri;
#pragma unroll
  for (int j=0;j<16;j++){
    const int gc = tc*64 + cc + j;
    const short b = f2bf(src[gr*256 + gc]);
    dN[gr*256 + gc] = b;
    t[cc + j][ri] = b;
  }
  __syncthreads();
  const int cr = tid >> 2;                // local transposed row (= source col)
#pragma unroll
  for (int j=0;j<16;j++){
    const int sr = cc + j;                // source row local
    dT[(tc*64 + cr)*256 + tr*64 + sr] = t[cr][sr];
  }
}

extern "C" void kernel_launch(void* const* d_in, const int* in_sizes, int n_in,
                              void* d_out, int out_size, void* d_ws, size_t ws_size,
                              hipStream_t stream)
{
  const float* x   = (const float*)d_in[0];
  const float* VW1 = (const float*)d_in[1];
  const float* Vb1 = (const float*)d_in[2];
  const float* VW2 = (const float*)d_in[3];
  const float* Vb2 = (const float*)d_in[4];
  const float* HW1 = (const float*)d_in[5];
  const float* Hb1 = (const float*)d_in[6];
  const float* HW2 = (const float*)d_in[7];
  const float* Hb2 = (const float*)d_in[8];
  const float* HW3 = (const float*)d_in[9];
  const float* Hb3 = (const float*)d_in[10];
  const float* uW1 = (const float*)d_in[11];
  const float* ub1 = (const float*)d_in[12];
  const float* uW2 = (const float*)d_in[13];
  const float* ub2 = (const float*)d_in[14];

  short* wsbf = (short*)d_ws;             // needs 4*65536*2 = 512 KB of d_ws

  cvt_w<<<32, 256, 0, stream>>>(VW2, HW2, wsbf);
  fused<<<NB/MS, NT, 0, stream>>>(x, VW1, Vb1, Vb2, HW1, Hb1, Hb2, HW3, Hb3,
                                  uW1, ub1, uW2, ub2,
                                  wsbf, wsbf + 65536, wsbf + 131072, wsbf + 196608,
                                  (float*)d_out);
}